// Round 9
// baseline (1242.432 us; speedup 1.0000x reference)
//
#include <hip/hip_runtime.h>
#include <math.h>

#define B_ 32
#define T_ 128
#define D_ 768
#define A_ 512
#define R_ 128
#define L_ 50

// ---------------------------------------------------------------------------
// Fused projection GEMM: HA/DA/HL/DL = ELU(X @ W + b) in one launch.
// ---------------------------------------------------------------------------
__global__ __launch_bounds__(256)
void proj_gemm_k(const float* __restrict__ X,
                 const float* __restrict__ Wha, const float* __restrict__ bha,
                 const float* __restrict__ Wda, const float* __restrict__ bda,
                 const float* __restrict__ Whl, const float* __restrict__ bhl,
                 const float* __restrict__ Wdl, const float* __restrict__ bdl,
                 float* __restrict__ HA, float* __restrict__ DA,
                 float* __restrict__ HL, float* __restrict__ DL)
{
    __shared__ float As[16][68];
    __shared__ float Bs[16][132];
    const int bx = blockIdx.x;
    const float *W, *bias; float* C; int ld, ncol;
    if (bx < 4)      { W = Wha; bias = bha; C = HA; ld = 512; ncol = bx * 128; }
    else if (bx < 8) { W = Wda; bias = bda; C = DA; ld = 512; ncol = (bx - 4) * 128; }
    else if (bx == 8){ W = Whl; bias = bhl; C = HL; ld = 128; ncol = 0; }
    else             { W = Wdl; bias = bdl; C = DL; ld = 128; ncol = 0; }
    const int m0 = blockIdx.y * 64;
    const int tid = threadIdx.x;
    const int tx = tid & 15, ry = tid >> 4;
    float acc[4][8] = {};
    for (int k0 = 0; k0 < 768; k0 += 16) {
        {
            int row = tid >> 2, kb = (tid & 3) * 4;
            float4 a = *(const float4*)&X[(size_t)(m0 + row) * 768 + k0 + kb];
            As[kb + 0][row] = a.x; As[kb + 1][row] = a.y;
            As[kb + 2][row] = a.z; As[kb + 3][row] = a.w;
        }
        {
            int kk = tid >> 4, c0 = (tid & 15) * 4;
            const float* Bp = &W[(size_t)(k0 + kk) * ld + ncol + c0];
            *(float4*)&Bs[kk][c0] = *(const float4*)&Bp[0];
            *(float4*)&Bs[kk][c0 + 64] = *(const float4*)&Bp[64];
        }
        __syncthreads();
#pragma unroll
        for (int kk = 0; kk < 16; ++kk) {
            float4 a4 = *(const float4*)&As[kk][ry * 4];
            float4 b0 = *(const float4*)&Bs[kk][tx * 4];
            float4 b1 = *(const float4*)&Bs[kk][tx * 4 + 64];
            float av[4] = { a4.x, a4.y, a4.z, a4.w };
            float bv[8] = { b0.x, b0.y, b0.z, b0.w, b1.x, b1.y, b1.z, b1.w };
#pragma unroll
            for (int i = 0; i < 4; ++i)
#pragma unroll
                for (int j = 0; j < 8; ++j)
                    acc[i][j] += av[i] * bv[j];
        }
        __syncthreads();
    }
    float bv0[8];
    {
        float4 q0 = *(const float4*)&bias[ncol + tx * 4];
        float4 q1 = *(const float4*)&bias[ncol + tx * 4 + 64];
        bv0[0] = q0.x; bv0[1] = q0.y; bv0[2] = q0.z; bv0[3] = q0.w;
        bv0[4] = q1.x; bv0[5] = q1.y; bv0[6] = q1.z; bv0[7] = q1.w;
    }
#pragma unroll
    for (int i = 0; i < 4; ++i) {
        int m = m0 + ry * 4 + i;
        size_t base = (size_t)m * ld + ncol;
        float o[8];
#pragma unroll
        for (int j = 0; j < 8; ++j) {
            float v = acc[i][j] + bv0[j];
            o[j] = v > 0.0f ? v : expm1f(v);
        }
        float4 s0 = { o[0], o[1], o[2], o[3] };
        float4 s1 = { o[4], o[5], o[6], o[7] };
        *(float4*)&C[base + tx * 4] = s0;
        *(float4*)&C[base + tx * 4 + 64] = s1;
    }
}

// ---------------------------------------------------------------------------
// fp32 GEMM, tile 64x128, 256 threads, 4x8 acc/thread, b128 LDS reads.
// ---------------------------------------------------------------------------
__global__ __launch_bounds__(256)
void gemm_k(const float* __restrict__ A, const float* __restrict__ B,
            const float* __restrict__ bias, float* __restrict__ C,
            int K, int lda, int ldb, int ldc,
            long long sA, long long sB, long long sC, long long c_outer, int flags)
{
    __shared__ float As[16][68];
    __shared__ float Bs[16][132];
    A += (size_t)blockIdx.z * sA;
    B += (size_t)blockIdx.z * sB;
    C += (size_t)blockIdx.z * sC;
    const int m0 = blockIdx.y * 64, n0 = blockIdx.x * 128;
    const int tid = threadIdx.x;
    const int tx = tid & 15, ry = tid >> 4;
    float acc[4][8] = {};
    for (int k0 = 0; k0 < K; k0 += 16) {
        {
            int row = tid >> 2, kb = (tid & 3) * 4;
            float4 a = *(const float4*)&A[(size_t)(m0 + row) * lda + k0 + kb];
            As[kb + 0][row] = a.x; As[kb + 1][row] = a.y;
            As[kb + 2][row] = a.z; As[kb + 3][row] = a.w;
        }
        if (!(flags & 4)) {
            int kk = tid >> 4, c0 = (tid & 15) * 4;
            const float* Bp = &B[(size_t)(k0 + kk) * ldb + n0 + c0];
            *(float4*)&Bs[kk][c0] = *(const float4*)&Bp[0];
            *(float4*)&Bs[kk][c0 + 64] = *(const float4*)&Bp[64];
        } else {
            int col = tid >> 1, kb = (tid & 1) * 8;
            const float* Bp = &B[(size_t)(n0 + col) * ldb + k0 + kb];
            float4 b0 = *(const float4*)&Bp[0];
            float4 b1 = *(const float4*)&Bp[4];
            Bs[kb + 0][col] = b0.x; Bs[kb + 1][col] = b0.y;
            Bs[kb + 2][col] = b0.z; Bs[kb + 3][col] = b0.w;
            Bs[kb + 4][col] = b1.x; Bs[kb + 5][col] = b1.y;
            Bs[kb + 6][col] = b1.z; Bs[kb + 7][col] = b1.w;
        }
        __syncthreads();
#pragma unroll
        for (int kk = 0; kk < 16; ++kk) {
            float4 a4 = *(const float4*)&As[kk][ry * 4];
            float4 b0 = *(const float4*)&Bs[kk][tx * 4];
            float4 b1 = *(const float4*)&Bs[kk][tx * 4 + 64];
            float av[4] = { a4.x, a4.y, a4.z, a4.w };
            float bv[8] = { b0.x, b0.y, b0.z, b0.w, b1.x, b1.y, b1.z, b1.w };
#pragma unroll
            for (int i = 0; i < 4; ++i)
#pragma unroll
                for (int j = 0; j < 8; ++j)
                    acc[i][j] += av[i] * bv[j];
        }
        __syncthreads();
    }
    float bv0[8] = {};
    if (flags & 1) {
        float4 q0 = *(const float4*)&bias[n0 + tx * 4];
        float4 q1 = *(const float4*)&bias[n0 + tx * 4 + 64];
        bv0[0] = q0.x; bv0[1] = q0.y; bv0[2] = q0.z; bv0[3] = q0.w;
        bv0[4] = q1.x; bv0[5] = q1.y; bv0[6] = q1.z; bv0[7] = q1.w;
    }
#pragma unroll
    for (int i = 0; i < 4; ++i) {
        int m = m0 + ry * 4 + i;
        size_t base = (size_t)(m >> 7) * c_outer + (size_t)(m & 127) * ldc + n0;
        float o[8];
#pragma unroll
        for (int j = 0; j < 8; ++j) {
            float v = acc[i][j] + bv0[j];
            if (flags & 2) v = v > 0.0f ? v : expm1f(v);
            o[j] = v;
        }
        float4 s0 = { o[0], o[1], o[2], o[3] };
        float4 s1 = { o[4], o[5], o[6], o[7] };
        *(float4*)&C[base + tx * 4] = s0;
        *(float4*)&C[base + tx * 4 + 64] = s1;
    }
}

// 128x128 per-batch transpose: DLt[b][s][j] = DL[b][j][s]
__global__ __launch_bounds__(256)
void transpose_k(const float* __restrict__ in, float* __restrict__ out)
{
    __shared__ float tile[32][33];
    int b = blockIdx.z;
    int bx = blockIdx.x, by = blockIdx.y;
    int tx = threadIdx.x, ty = threadIdx.y; // (32,8)
    const float* src = in + (size_t)b * T_ * R_;
    float* dst = out + (size_t)b * T_ * R_;
#pragma unroll
    for (int r = 0; r < 4; ++r)
        tile[ty + 8 * r][tx] = src[(size_t)(by * 32 + ty + 8 * r) * 128 + bx * 32 + tx];
    __syncthreads();
#pragma unroll
    for (int r = 0; r < 4; ++r)
        dst[(size_t)(bx * 32 + ty + 8 * r) * 128 + by * 32 + tx] = tile[tx][ty + 8 * r];
}

// log_softmax over dim 1 (i) of (32,128,128), in place. thread = column j.
__global__ __launch_bounds__(128)
void arc_logsoftmax_k(float* __restrict__ arc)
{
    int b = blockIdx.x, j = threadIdx.x;
    float* base = arc + (size_t)b * T_ * T_ + j;
    float m = -INFINITY;
    for (int i = 0; i < T_; ++i) m = fmaxf(m, base[(size_t)i * T_]);
    float s = 0.0f;
    for (int i = 0; i < T_; ++i) s += expf(base[(size_t)i * T_] - m);
    float ls = m + logf(s);
    for (int i = 0; i < T_; ++i) base[(size_t)i * T_] -= ls;
}

// ---------------------------------------------------------------------------
// Fused TL + lab kernel v2: two chained gemm_k bodies (validated r8).
// ---------------------------------------------------------------------------
__global__ __launch_bounds__(256)
void tl_lab_k(const float* __restrict__ HL, const float* __restrict__ Ul,
              const float* __restrict__ dlt, float* __restrict__ E)
{
    __shared__ float Ts[128 * 68];  // 34816 B: [s][row], k-major for Phase B
    __shared__ float As[16][68];
    __shared__ float Bs[16][132];
    const int l = blockIdx.x, b = blockIdx.y;
    const int m0 = blockIdx.z * 64;
    const int tid = threadIdx.x;
    const int tx = tid & 15, ry = tid >> 4;
    const float* Apan = HL + (size_t)b * 16384 + (size_t)m0 * 128;
    const float* Bpan = Ul + (size_t)l * 16384;
    const float* Dpan = dlt + (size_t)b * 16384;
    float acc[4][8] = {};
    // ---- Phase A: T64 = HL_b[m0:m0+64] @ Ul_l (gemm_k body, K=128) ----
    for (int k0 = 0; k0 < 128; k0 += 16) {
        {
            int row = tid >> 2, kb = (tid & 3) * 4;
            float4 a = *(const float4*)&Apan[(size_t)row * 128 + k0 + kb];
            As[kb + 0][row] = a.x; As[kb + 1][row] = a.y;
            As[kb + 2][row] = a.z; As[kb + 3][row] = a.w;
        }
        {
            int kk = tid >> 4, c0 = (tid & 15) * 4;
            const float* Bp = &Bpan[(size_t)(k0 + kk) * 128 + c0];
            *(float4*)&Bs[kk][c0] = *(const float4*)&Bp[0];
            *(float4*)&Bs[kk][c0 + 64] = *(const float4*)&Bp[64];
        }
        __syncthreads();
#pragma unroll
        for (int kk = 0; kk < 16; ++kk) {
            float4 a4 = *(const float4*)&As[kk][ry * 4];
            float4 b0 = *(const float4*)&Bs[kk][tx * 4];
            float4 b1 = *(const float4*)&Bs[kk][tx * 4 + 64];
            float av[4] = { a4.x, a4.y, a4.z, a4.w };
            float bv[8] = { b0.x, b0.y, b0.z, b0.w, b1.x, b1.y, b1.z, b1.w };
#pragma unroll
            for (int i = 0; i < 4; ++i)
#pragma unroll
                for (int j = 0; j < 8; ++j)
                    acc[i][j] += av[i] * bv[j];
        }
        __syncthreads();
    }
    // ---- park T64 into Ts[s][row] (k-major; one-time 8 writes/thread) ----
#pragma unroll
    for (int j = 0; j < 8; ++j) {
        int col = (j < 4) ? (tx * 4 + j) : (64 + tx * 4 + j - 4);
        float4 w = { acc[0][j], acc[1][j], acc[2][j], acc[3][j] };
        *(float4*)&Ts[col * 68 + ry * 4] = w;
#pragma unroll
        for (int i = 0; i < 4; ++i) acc[i][j] = 0.0f;
    }
    __syncthreads();
    // ---- Phase B: E64 = T64 @ DLt_b (gemm_k body; A from Ts, no restage) ----
    for (int k0 = 0; k0 < 128; k0 += 16) {
        {
            int kk = tid >> 4, c0 = (tid & 15) * 4;
            const float* Bp = &Dpan[(size_t)(k0 + kk) * 128 + c0];
            *(float4*)&Bs[kk][c0] = *(const float4*)&Bp[0];
            *(float4*)&Bs[kk][c0 + 64] = *(const float4*)&Bp[64];
        }
        __syncthreads();
#pragma unroll
        for (int kk = 0; kk < 16; ++kk) {
            float4 a4 = *(const float4*)&Ts[(k0 + kk) * 68 + ry * 4];
            float4 b0 = *(const float4*)&Bs[kk][tx * 4];
            float4 b1 = *(const float4*)&Bs[kk][tx * 4 + 64];
            float av[4] = { a4.x, a4.y, a4.z, a4.w };
            float bv[8] = { b0.x, b0.y, b0.z, b0.w, b1.x, b1.y, b1.z, b1.w };
#pragma unroll
            for (int i = 0; i < 4; ++i)
#pragma unroll
                for (int j = 0; j < 8; ++j)
                    acc[i][j] += av[i] * bv[j];
        }
        __syncthreads();
    }
    float* base = E + ((size_t)b * L_ + l) * 16384 + (size_t)m0 * 128;
#pragma unroll
    for (int i = 0; i < 4; ++i) {
        float4 s0 = { acc[i][0], acc[i][1], acc[i][2], acc[i][3] };
        float4 s1 = { acc[i][4], acc[i][5], acc[i][6], acc[i][7] };
        *(float4*)&base[(size_t)(ry * 4 + i) * 128 + tx * 4] = s0;
        *(float4*)&base[(size_t)(ry * 4 + i) * 128 + tx * 4 + 64] = s1;
    }
}

// energy combine + fused score/labmax for MST.
__global__ __launch_bounds__(256)
void energy_combine_k(float* __restrict__ E, const float* __restrict__ narc,
                      float* __restrict__ score_g, unsigned char* __restrict__ labmax_g)
{
    int g = blockIdx.x * 256 + threadIdx.x; // 0..524287
    int b = g >> 14;
    int ij = g & 16383;
    float* base = E + (size_t)b * L_ * T_ * T_ + ij;
    float v[L_];
    float m = -INFINITY;
    int am = 0;
#pragma unroll
    for (int l = 0; l < L_; ++l) {
        v[l] = base[(size_t)l * T_ * T_];
        if (v[l] > m) { m = v[l]; am = l; }
    }
    float s = 0.0f;
#pragma unroll
    for (int l = 0; l < L_; ++l) s += expf(v[l] - m);
    float ls = m + logf(s);
    float na = narc[(size_t)b * T_ * T_ + ij];
#pragma unroll
    for (int l = 0; l < L_; ++l) base[(size_t)l * T_ * T_] = expf(na + v[l] - ls);
    int i = ij >> 7, j = ij & 127;
    score_g[(size_t)b * 16384 + ij] = (i == j) ? 0.0f : expf(na + m - ls);
    labmax_g[(size_t)b * 16384 + ij] = (unsigned char)am;
}

// ---------------------------------------------------------------------------
// Chu-Liu-Edmonds MST decode. r9: same r7 pass structure (validated), with
// latency-targeted surgery:
//  - Phase 1/2 member loops quad-unrolled with MANUALLY HOISTED loads
//    (safe: each lane touches only its own row/col; a cycle's rep entries
//    are only read while scanning that cycle, before its segend store).
//    List padded with cid=255 sentinels; survivor lim = 128 so pads never
//    match. 4x memory-level parallelism on the dominant loops.
//  - rep-column rescans: lane-per-rep 127-iter pipelined loop (store-free)
//    replacing per-rep shfl butterflies. Tie-break (smallest index,
//    root-first) identical.
//  - Lnode/Lcid packed into ushort Lpk.
// ---------------------------------------------------------------------------
__global__ __launch_bounds__(256)
void mst_k(const float* __restrict__ score_g, const unsigned char* __restrict__ labmax_g,
           float* __restrict__ heads, float* __restrict__ tags)
{
    const int b = blockIdx.x, t = threadIdx.x;
    __shared__ float score[128 * 129];          // 66 KB, stride 129
    __shared__ unsigned short oio[128 * 129];   // 33 KB: oin | (oout<<8)
    __shared__ unsigned char pstL[96 * 128];    // 12 KB: parents per pass-level
    __shared__ unsigned char kynL[96 * 128];    // 12 KB: key cand per pass-level
    __shared__ int parents[128];
    __shared__ int fe[128]; // -2 = absent; -1 = root marker
    __shared__ float pmx[128];
    __shared__ int pp[128];        // init scan; reused as pnew[] in rescans
    __shared__ float cwacc[128];   // cycle weight by cid
    __shared__ int cnt[128];
    __shared__ int offarr[128];
    __shared__ float Lsub[136];
    __shared__ unsigned short Lpk[136];         // node | (cid<<8)
    __shared__ unsigned char cidarr[128], oncyc[128], replist[72];

    // ---- phase 0: stage score (padded), init oio/fe ----
    {
        const float4* src = (const float4*)(score_g + (size_t)b * 16384);
        for (int i = t; i < 4096; i += 256) {
            float4 v = src[i];
            int r = i >> 5, c = (i & 31) * 4;
            float* d = &score[r * 129 + c];
            d[0] = v.x; d[1] = v.y; d[2] = v.z; d[3] = v.w;
        }
    }
    for (int i = t; i < 16384; i += 256) {
        int r = i >> 7, c = i & 127;
        oio[r * 129 + c] = (unsigned short)(r | (c << 8));
    }
    if (t < 128) { fe[t] = -2; oncyc[t] = 0; }
    __syncthreads();
    if (t < 128) score[t * 129 + t] = -INFINITY; // diag never read elsewhere
    __syncthreads();
    // ---- initial full parent scan (split across 256 threads) ----
    float mxl = 0.0f; int pl = 0;
    if (t >= 128) {
        int col = t - 128;
        float mx = -INFINITY; int pu = 64;
        if (col != 0) {
            mx = score[64 * 129 + col];
#pragma unroll 16
            for (int n2 = 65; n2 < 128; ++n2) {
                float sc = score[n2 * 129 + col];
                if (sc > mx) { mx = sc; pu = n2; }
            }
        }
        pmx[col] = mx; pp[col] = pu;
    } else if (t != 0) {
        mxl = score[t]; pl = 0; // row 0 initial (root candidate)
#pragma unroll 16
        for (int n2 = 1; n2 < 64; ++n2) {
            float sc = score[n2 * 129 + t];
            if (sc > mxl) { mxl = sc; pl = n2; }
        }
    }
    __syncthreads();
    if (t == 0) parents[0] = -1;
    else if (t < 128) parents[t] = (pmx[t] > mxl) ? pp[t] : pl;
    __syncthreads(); // ---- barrier A: wave 0 takes over ----

    if (t < 64) {
        const int n0 = t, n1 = t + 64;
        int p0 = parents[n0], p1 = parents[n1];
        int c0 = 1, c1 = 1;       // active flags
        int r0 = n0, r1 = n1;     // rep_of mirrors
        int lev = 0, nact = 128, pass = 0;
        const unsigned long long lmask = (1ull << t) - 1ull;
        for (;;) {
            // --- doubling: a = 2^rounds-step ancestor, m = path-min ---
            int rounds = 32 - __clz(nact - 1);
            int a0 = (n0 == 0 || !c0) ? 0 : p0;
            int a1 = (!c1) ? 0 : p1;
            int m0 = n0, m1 = n1;
            for (int s = 0; s < rounds; ++s) {
                int pk0 = (a0 << 7) | m0;
                int pk1 = (a1 << 7) | m1;
                int q00 = __shfl(pk0, a0 & 63, 64);
                int q01 = __shfl(pk1, a0 & 63, 64);
                int q10 = __shfl(pk0, a1 & 63, 64);
                int q11 = __shfl(pk1, a1 & 63, 64);
                int g0 = (a0 & 64) ? q01 : q00;
                int g1 = (a1 & 64) ? q11 : q10;
                a0 = g0 >> 7; int gm0 = g0 & 127; m0 = gm0 < m0 ? gm0 : m0;
                a1 = g1 >> 7; int gm1 = g1 & 127; m1 = gm1 < m1 ? gm1 : m1;
            }
            int pred0 = (n0 >= 1) && c0 && (a0 != 0);
            int pred1 = c1 && (a1 != 0);
            unsigned long long bal0 = __ballot(pred0);
            unsigned long long bal1 = __ballot(pred1);
            if (bal0 == 0ull && bal1 == 0ull) {
                // base case: no cycles — emit final edges for active nodes
                if (n0 == 0) fe[0] = -1;
                else if (c0) { int w = oio[p0 * 129 + n0]; fe[w >> 8] = w & 255; }
                if (c1) { int w = oio[p1 * 129 + n1]; fe[w >> 8] = w & 255; }
                __threadfence_block();
                break;
            }
            // --- mark all cycle nodes; zero per-pass accumulators ---
            unsigned char ep = (unsigned char)(++pass);
            if (pred0) oncyc[a0] = ep;
            if (pred1) oncyc[a1] = ep;
            cnt[n0] = 0; cnt[n1] = 0;
            cwacc[n0] = 0.0f; cwacc[n1] = 0.0f;
            __threadfence_block(); // fence A
            int onc0 = c0 && (oncyc[n0] == ep);
            int onc1 = c1 && (oncyc[n1] == ep);
            const int cid0 = m0, cid1 = m1; // valid when onc
            cidarr[n0] = onc0 ? (unsigned char)cid0 : 0xFF;
            cidarr[n1] = onc1 ? (unsigned char)cid1 : 0xFF;
            // rep ballots + ordinals (needed for replist + Phase 2)
            int rp0 = onc0 && (n0 == cid0);
            int rp1 = onc1 && (n1 == cid1);
            unsigned long long q0 = __ballot(rp0);
            unsigned long long q1 = __ballot(rp1);
            int ncyc = (int)__popcll(q0) + (int)__popcll(q1);
            if (rp0) replist[(int)__popcll(q0 & lmask)] = (unsigned char)n0;
            if (rp1) replist[(int)__popcll(q0) + (int)__popcll(q1 & lmask)] = (unsigned char)n1;
            float sub0 = 0.0f, sub1 = 0.0f;
            int rk0 = 0, rk1 = 0;
            if (onc0) { sub0 = score[p0 * 129 + n0]; rk0 = atomicAdd(&cnt[cid0], 1); atomicAdd(&cwacc[cid0], sub0); }
            if (onc1) { sub1 = score[p1 * 129 + n1]; rk1 = atomicAdd(&cnt[cid1], 1); atomicAdd(&cwacc[cid1], sub1); }
            __threadfence_block(); // fence B: cnt/cidarr/cwacc final
            // --- packed wave scan of cnt -> segment offsets (cid order) ---
            int x0 = cnt[n0], x1 = cnt[n1];
            int v = (x0 & 0xFFFF) | (x1 << 16);
            for (int off = 1; off < 64; off <<= 1) {
                int u = __shfl(v, t >= off ? t - off : 0, 64);
                v += (t >= off) ? u : 0;
            }
            int tot = __shfl(v, 63, 64);
            int Mtot = (tot & 0xFFFF) + (tot >> 16);
            offarr[n0] = (v & 0xFFFF) - x0;
            offarr[n1] = (tot & 0xFFFF) + ((v >> 16) & 0xFFFF) - x1;
            __threadfence_block(); // fence C: offsets visible
            if (onc0) { int sl = offarr[cid0] + rk0; Lpk[sl] = (unsigned short)(n0 | (cid0 << 8)); Lsub[sl] = sub0; }
            if (onc1) { int sl = offarr[cid1] + rk1; Lpk[sl] = (unsigned short)(n1 | (cid1 << 8)); Lsub[sl] = sub1; }
            if (t < 4) { Lpk[Mtot + t] = (unsigned short)(255 << 8); Lsub[Mtot + t] = 0.0f; } // pads
            // --- save pass-level state ---
            int rc0 = cidarr[r0], rc1 = cidarr[r1];
            if (lev < 96) {
                pstL[lev * 128 + n0] = (unsigned char)p0;
                pstL[lev * 128 + n1] = (unsigned char)p1;
                kynL[lev * 128 + n0] = (rc0 != 0xFF) ? (unsigned char)r0 : 0xFF;
                kynL[lev * 128 + n1] = (rc1 != 0xFF) ? (unsigned char)r1 : 0xFF;
            }
            if (rc0 != 0xFF) r0 = rc0;
            if (rc1 != 0xFF) r1 = rc1;
            __threadfence_block(); // fence D: list + pads + replist visible
            // --- Phase 1: quad-unrolled, hoisted loads ---
            {
                int lim0 = c0 ? (onc0 ? cid0 : 128) : -1;
                int lim1 = c1 ? (onc1 ? cid1 : 128) : -1;
                float inw0 = -INFINITY, outw0 = -INFINITY;
                float inw1 = -INFINITY, outw1 = -INFINITY;
                int qi0 = 0, qo0 = 0, qi1 = 0, qo1 = 0;
                for (int i = 0; i < Mtot; i += 4) {
                    // hoisted loads for 4 members + next-cid
                    int pkA = Lpk[i], pkB = Lpk[i + 1], pkC = Lpk[i + 2], pkD = Lpk[i + 3];
                    int dE = Lpk[i + 4] >> 8;
                    float sbA = Lsub[i], sbB = Lsub[i + 1], sbC = Lsub[i + 2], sbD = Lsub[i + 3];
                    int uA = pkA & 255, dA = pkA >> 8;
                    int uB = pkB & 255, dB = pkB >> 8;
                    int uC = pkC & 255, dC = pkC >> 8;
                    int uD = pkD & 255, dD = pkD >> 8;
                    float siA0 = score[uA * 129 + n0], soA0 = score[n0 * 129 + uA];
                    float siA1 = score[uA * 129 + n1], soA1 = score[n1 * 129 + uA];
                    int wiA0 = oio[uA * 129 + n0], woA0 = oio[n0 * 129 + uA];
                    int wiA1 = oio[uA * 129 + n1], woA1 = oio[n1 * 129 + uA];
                    float siB0 = score[uB * 129 + n0], soB0 = score[n0 * 129 + uB];
                    float siB1 = score[uB * 129 + n1], soB1 = score[n1 * 129 + uB];
                    int wiB0 = oio[uB * 129 + n0], woB0 = oio[n0 * 129 + uB];
                    int wiB1 = oio[uB * 129 + n1], woB1 = oio[n1 * 129 + uB];
                    float siC0 = score[uC * 129 + n0], soC0 = score[n0 * 129 + uC];
                    float siC1 = score[uC * 129 + n1], soC1 = score[n1 * 129 + uC];
                    int wiC0 = oio[uC * 129 + n0], woC0 = oio[n0 * 129 + uC];
                    int wiC1 = oio[uC * 129 + n1], woC1 = oio[n1 * 129 + uC];
                    float siD0 = score[uD * 129 + n0], soD0 = score[n0 * 129 + uD];
                    float siD1 = score[uD * 129 + n1], soD1 = score[n1 * 129 + uD];
                    int wiD0 = oio[uD * 129 + n0], woD0 = oio[n0 * 129 + uD];
                    int wiD1 = oio[uD * 129 + n1], woD1 = oio[n1 * 129 + uD];
                    float cwA = cwacc[dA & 127], cwB = cwacc[dB & 127];
                    float cwC = cwacc[dC & 127], cwD = cwacc[dD & 127];
                    // element A
                    if (dA < lim0) {
                        if (siA0 > inw0) { inw0 = siA0; qi0 = wiA0; }
                        float so = soA0 - sbA;
                        if (so > outw0) { outw0 = so; qo0 = woA0; }
                    }
                    if (dA < lim1) {
                        if (siA1 > inw1) { inw1 = siA1; qi1 = wiA1; }
                        float so = soA1 - sbA;
                        if (so > outw1) { outw1 = so; qo1 = woA1; }
                    }
                    if (dB != dA) {
                        if (dA < lim0) {
                            score[dA * 129 + n0] = inw0; oio[dA * 129 + n0] = (unsigned short)qi0;
                            score[n0 * 129 + dA] = cwA + outw0; oio[n0 * 129 + dA] = (unsigned short)qo0;
                        }
                        if (dA < lim1) {
                            score[dA * 129 + n1] = inw1; oio[dA * 129 + n1] = (unsigned short)qi1;
                            score[n1 * 129 + dA] = cwA + outw1; oio[n1 * 129 + dA] = (unsigned short)qo1;
                        }
                        inw0 = -INFINITY; outw0 = -INFINITY; inw1 = -INFINITY; outw1 = -INFINITY;
                    }
                    // element B
                    if (dB < lim0) {
                        if (siB0 > inw0) { inw0 = siB0; qi0 = wiB0; }
                        float so = soB0 - sbB;
                        if (so > outw0) { outw0 = so; qo0 = woB0; }
                    }
                    if (dB < lim1) {
                        if (siB1 > inw1) { inw1 = siB1; qi1 = wiB1; }
                        float so = soB1 - sbB;
                        if (so > outw1) { outw1 = so; qo1 = woB1; }
                    }
                    if (dC != dB) {
                        if (dB < lim0) {
                            score[dB * 129 + n0] = inw0; oio[dB * 129 + n0] = (unsigned short)qi0;
                            score[n0 * 129 + dB] = cwB + outw0; oio[n0 * 129 + dB] = (unsigned short)qo0;
                        }
                        if (dB < lim1) {
                            score[dB * 129 + n1] = inw1; oio[dB * 129 + n1] = (unsigned short)qi1;
                            score[n1 * 129 + dB] = cwB + outw1; oio[n1 * 129 + dB] = (unsigned short)qo1;
                        }
                        inw0 = -INFINITY; outw0 = -INFINITY; inw1 = -INFINITY; outw1 = -INFINITY;
                    }
                    // element C
                    if (dC < lim0) {
                        if (siC0 > inw0) { inw0 = siC0; qi0 = wiC0; }
                        float so = soC0 - sbC;
                        if (so > outw0) { outw0 = so; qo0 = woC0; }
                    }
                    if (dC < lim1) {
                        if (siC1 > inw1) { inw1 = siC1; qi1 = wiC1; }
                        float so = soC1 - sbC;
                        if (so > outw1) { outw1 = so; qo1 = woC1; }
                    }
                    if (dD != dC) {
                        if (dC < lim0) {
                            score[dC * 129 + n0] = inw0; oio[dC * 129 + n0] = (unsigned short)qi0;
                            score[n0 * 129 + dC] = cwC + outw0; oio[n0 * 129 + dC] = (unsigned short)qo0;
                        }
                        if (dC < lim1) {
                            score[dC * 129 + n1] = inw1; oio[dC * 129 + n1] = (unsigned short)qi1;
                            score[n1 * 129 + dC] = cwC + outw1; oio[n1 * 129 + dC] = (unsigned short)qo1;
                        }
                        inw0 = -INFINITY; outw0 = -INFINITY; inw1 = -INFINITY; outw1 = -INFINITY;
                    }
                    // element D
                    if (dD < lim0) {
                        if (siD0 > inw0) { inw0 = siD0; qi0 = wiD0; }
                        float so = soD0 - sbD;
                        if (so > outw0) { outw0 = so; qo0 = woD0; }
                    }
                    if (dD < lim1) {
                        if (siD1 > inw1) { inw1 = siD1; qi1 = wiD1; }
                        float so = soD1 - sbD;
                        if (so > outw1) { outw1 = so; qo1 = woD1; }
                    }
                    if (dE != dD) {
                        if (dD < lim0) {
                            score[dD * 129 + n0] = inw0; oio[dD * 129 + n0] = (unsigned short)qi0;
                            score[n0 * 129 + dD] = cwD + outw0; oio[n0 * 129 + dD] = (unsigned short)qo0;
                        }
                        if (dD < lim1) {
                            score[dD * 129 + n1] = inw1; oio[dD * 129 + n1] = (unsigned short)qi1;
                            score[n1 * 129 + dD] = cwD + outw1; oio[n1 * 129 + dD] = (unsigned short)qo1;
                        }
                        inw0 = -INFINITY; outw0 = -INFINITY; inw1 = -INFINITY; outw1 = -INFINITY;
                    }
                }
            }
            __threadfence_block(); // fence E: Phase 1 visible
            // --- Phase 2: rep lanes vs strictly-later cycles (quad) ---
            if (ncyc >= 2) {
                float inw0 = -INFINITY, outw0 = -INFINITY;
                float inw1 = -INFINITY, outw1 = -INFINITY;
                int qi0 = 0, qo0 = 0, qi1 = 0, qo1 = 0;
                int lo0 = rp0 ? cid0 : 999, lo1 = rp1 ? cid1 : 999;
                for (int i = 0; i < Mtot; i += 4) {
                    int pkA = Lpk[i], pkB = Lpk[i + 1], pkC = Lpk[i + 2], pkD = Lpk[i + 3];
                    int dE = Lpk[i + 4] >> 8;
                    float sbA = Lsub[i], sbB = Lsub[i + 1], sbC = Lsub[i + 2], sbD = Lsub[i + 3];
                    int uA = pkA & 255, dA = pkA >> 8;
                    int uB = pkB & 255, dB = pkB >> 8;
                    int uC = pkC & 255, dC = pkC >> 8;
                    int uD = pkD & 255, dD = pkD >> 8;
                    float siA0 = score[uA * 129 + n0], soA0 = score[n0 * 129 + uA];
                    float siA1 = score[uA * 129 + n1], soA1 = score[n1 * 129 + uA];
                    int wiA0 = oio[uA * 129 + n0], woA0 = oio[n0 * 129 + uA];
                    int wiA1 = oio[uA * 129 + n1], woA1 = oio[n1 * 129 + uA];
                    float siB0 = score[uB * 129 + n0], soB0 = score[n0 * 129 + uB];
                    float siB1 = score[uB * 129 + n1], soB1 = score[n1 * 129 + uB];
                    int wiB0 = oio[uB * 129 + n0], woB0 = oio[n0 * 129 + uB];
                    int wiB1 = oio[uB * 129 + n1], woB1 = oio[n1 * 129 + uB];
                    float siC0 = score[uC * 129 + n0], soC0 = score[n0 * 129 + uC];
                    float siC1 = score[uC * 129 + n1], soC1 = score[n1 * 129 + uC];
                    int wiC0 = oio[uC * 129 + n0], woC0 = oio[n0 * 129 + uC];
                    int wiC1 = oio[uC * 129 + n1], woC1 = oio[n1 * 129 + uC];
                    float siD0 = score[uD * 129 + n0], soD0 = score[n0 * 129 + uD];
                    float siD1 = score[uD * 129 + n1], soD1 = score[n1 * 129 + uD];
                    int wiD0 = oio[uD * 129 + n0], woD0 = oio[n0 * 129 + uD];
                    int wiD1 = oio[uD * 129 + n1], woD1 = oio[n1 * 129 + uD];
                    float cwA = cwacc[dA & 127], cwB = cwacc[dB & 127];
                    float cwC = cwacc[dC & 127], cwD = cwacc[dD & 127];
                    // element A
                    int eA0 = (dA < 255) && (dA > lo0), eA1 = (dA < 255) && (dA > lo1);
                    if (eA0) {
                        if (siA0 > inw0) { inw0 = siA0; qi0 = wiA0; }
                        float so = soA0 - sbA;
                        if (so > outw0) { outw0 = so; qo0 = woA0; }
                    }
                    if (eA1) {
                        if (siA1 > inw1) { inw1 = siA1; qi1 = wiA1; }
                        float so = soA1 - sbA;
                        if (so > outw1) { outw1 = so; qo1 = woA1; }
                    }
                    if (dB != dA) {
                        if (eA0) {
                            score[dA * 129 + n0] = inw0; oio[dA * 129 + n0] = (unsigned short)qi0;
                            score[n0 * 129 + dA] = cwA + outw0; oio[n0 * 129 + dA] = (unsigned short)qo0;
                        }
                        if (eA1) {
                            score[dA * 129 + n1] = inw1; oio[dA * 129 + n1] = (unsigned short)qi1;
                            score[n1 * 129 + dA] = cwA + outw1; oio[n1 * 129 + dA] = (unsigned short)qo1;
                        }
                        inw0 = -INFINITY; outw0 = -INFINITY; inw1 = -INFINITY; outw1 = -INFINITY;
                    }
                    // element B
                    int eB0 = (dB < 255) && (dB > lo0), eB1 = (dB < 255) && (dB > lo1);
                    if (eB0) {
                        if (siB0 > inw0) { inw0 = siB0; qi0 = wiB0; }
                        float so = soB0 - sbB;
                        if (so > outw0) { outw0 = so; qo0 = woB0; }
                    }
                    if (eB1) {
                        if (siB1 > inw1) { inw1 = siB1; qi1 = wiB1; }
                        float so = soB1 - sbB;
                        if (so > outw1) { outw1 = so; qo1 = woB1; }
                    }
                    if (dC != dB) {
                        if (eB0) {
                            score[dB * 129 + n0] = inw0; oio[dB * 129 + n0] = (unsigned short)qi0;
                            score[n0 * 129 + dB] = cwB + outw0; oio[n0 * 129 + dB] = (unsigned short)qo0;
                        }
                        if (eB1) {
                            score[dB * 129 + n1] = inw1; oio[dB * 129 + n1] = (unsigned short)qi1;
                            score[n1 * 129 + dB] = cwB + outw1; oio[n1 * 129 + dB] = (unsigned short)qo1;
                        }
                        inw0 = -INFINITY; outw0 = -INFINITY; inw1 = -INFINITY; outw1 = -INFINITY;
                    }
                    // element C
                    int eC0 = (dC < 255) && (dC > lo0), eC1 = (dC < 255) && (dC > lo1);
                    if (eC0) {
                        if (siC0 > inw0) { inw0 = siC0; qi0 = wiC0; }
                        float so = soC0 - sbC;
                        if (so > outw0) { outw0 = so; qo0 = woC0; }
                    }
                    if (eC1) {
                        if (siC1 > inw1) { inw1 = siC1; qi1 = wiC1; }
                        float so = soC1 - sbC;
                        if (so > outw1) { outw1 = so; qo1 = woC1; }
                    }
                    if (dD != dC) {
                        if (eC0) {
                            score[dC * 129 + n0] = inw0; oio[dC * 129 + n0] = (unsigned short)qi0;
                            score[n0 * 129 + dC] = cwC + outw0; oio[n0 * 129 + dC] = (unsigned short)qo0;
                        }
                        if (eC1) {
                            score[dC * 129 + n1] = inw1; oio[dC * 129 + n1] = (unsigned short)qi1;
                            score[n1 * 129 + dC] = cwC + outw1; oio[n1 * 129 + dC] = (unsigned short)qo1;
                        }
                        inw0 = -INFINITY; outw0 = -INFINITY; inw1 = -INFINITY; outw1 = -INFINITY;
                    }
                    // element D
                    int eD0 = (dD < 255) && (dD > lo0), eD1 = (dD < 255) && (dD > lo1);
                    if (eD0) {
                        if (siD0 > inw0) { inw0 = siD0; qi0 = wiD0; }
                        float so = soD0 - sbD;
                        if (so > outw0) { outw0 = so; qo0 = woD0; }
                    }
                    if (eD1) {
                        if (siD1 > inw1) { inw1 = siD1; qi1 = wiD1; }
                        float so = soD1 - sbD;
                        if (so > outw1) { outw1 = so; qo1 = woD1; }
                    }
                    if (dE != dD) {
                        if (eD0) {
                            score[dD * 129 + n0] = inw0; oio[dD * 129 + n0] = (unsigned short)qi0;
                            score[n0 * 129 + dD] = cwD + outw0; oio[n0 * 129 + dD] = (unsigned short)qo0;
                        }
                        if (eD1) {
                            score[dD * 129 + n1] = inw1; oio[dD * 129 + n1] = (unsigned short)qi1;
                            score[n1 * 129 + dD] = cwD + outw1; oio[n1 * 129 + dD] = (unsigned short)qo1;
                        }
                        inw0 = -INFINITY; outw0 = -INFINITY; inw1 = -INFINITY; outw1 = -INFINITY;
                    }
                }
                __threadfence_block(); // fence F: Phase 2 visible
            }
            // --- deactivate dying members; remap parents into reps ---
            if (onc0 && n0 != cid0) c0 = 0;
            if (onc1 && n1 != cid1) c1 = 0;
            if (c0 && n0 != 0) { int cp = cidarr[p0]; if (cp != 0xFF) p0 = cp; }
            if (c1)            { int cp = cidarr[p1]; if (cp != 0xFF) p1 = cp; }
            // --- surviving reps: lane-per-rep column rescan (store-free) ---
            {
                unsigned long long am0 = __ballot(c0);
                unsigned long long am1 = __ballot(c1);
                if (t < ncyc) {
                    int rep = replist[t];
                    float mx = score[rep]; // row 0 = root candidate
                    int par = 0;
#pragma unroll 4
                    for (int x = 1; x < 128; ++x) {
                        int alive = (x < 64) ? (int)((am0 >> x) & 1ull)
                                             : (int)((am1 >> (x - 64)) & 1ull);
                        float sc = score[x * 129 + rep];
                        if (alive && x != rep && sc > mx) { mx = sc; par = x; }
                    }
                    pp[rep] = par;
                }
                __threadfence_block(); // fence G: pp visible
                if (c0 && onc0) p0 = pp[n0];
                if (c1 && onc1) p1 = pp[n1];
            }
            nact -= (Mtot - ncyc);
            ++lev;
        }
        // --- unwind: per-pass levels, disjoint parallel walks ---
        int ltop = lev < 96 ? lev : 96;
        for (int l2 = ltop - 1; l2 >= 0; --l2) {
            int ky0 = kynL[l2 * 128 + n0], ky1 = kynL[l2 * 128 + n1];
            int cand0 = (ky0 != 0xFF) && (fe[n0] != -2);
            int cand1 = (ky1 != 0xFF) && (fe[n1] != -2);
            if (cand0) {
                int key = ky0;
                int prev = pstL[l2 * 128 + key];
                int guard = 0;
                while (prev != key && guard++ < 130) {
                    int pp2 = pstL[l2 * 128 + prev];
                    int w = oio[pp2 * 129 + prev];
                    fe[w >> 8] = w & 255;
                    prev = pp2;
                }
            }
            if (cand1) {
                int key = ky1;
                int prev = pstL[l2 * 128 + key];
                int guard = 0;
                while (prev != key && guard++ < 130) {
                    int pp2 = pstL[l2 * 128 + prev];
                    int w = oio[pp2 * 129 + prev];
                    fe[w >> 8] = w & 255;
                    prev = pp2;
                }
            }
            __threadfence_block();
        }
    }
    __syncthreads(); // ---- barrier B: waves 1-3 rejoin ----

    // --- emit heads / head_type ---
    if (t < 128) {
        int f = fe[t];
        float h, ht;
        if (f != -2) {
            h = (float)f;
            int prow = (f < 0) ? 127 : f; // numpy negative-index semantics for root
            ht = (float)(int)labmax_g[(size_t)b * 16384 + prow * 128 + t];
        } else { h = 0.0f; ht = 1.0f; }
        heads[b * 128 + t] = h;
        tags[b * 128 + t] = ht;
    }
}

extern "C" void kernel_launch(void* const* d_in, const int* in_sizes, int n_in,
                              void* d_out, int out_size, void* d_ws, size_t ws_size,
                              hipStream_t stream)
{
    const float* X   = (const float*)d_in[0];
    const float* Wha = (const float*)d_in[1];
    const float* bha = (const float*)d_in[2];
    const float* Wda = (const float*)d_in[3];
    const float* bda = (const float*)d_in[4];
    const float* Ua  = (const float*)d_in[5];
    const float* Whl = (const float*)d_in[6];
    const float* bhl = (const float*)d_in[7];
    const float* Wdl = (const float*)d_in[8];
    const float* bdl = (const float*)d_in[9];
    const float* Ul  = (const float*)d_in[10];
    // d_in[11] = mask: all-ones in this problem; length = 128 per batch.

    char* ws = (char*)d_ws;
    float* HA    = (float*)(ws + (size_t)0);
    float* DA    = (float*)(ws + ((size_t)8 << 20));
    float* TA    = (float*)(ws + ((size_t)16 << 20));
    float* HL    = (float*)(ws + ((size_t)24 << 20));
    float* DL    = (float*)(ws + ((size_t)26 << 20));
    float* DLt   = (float*)(ws + ((size_t)28 << 20));
    float* ARC   = (float*)(ws + ((size_t)30 << 20));
    float* SCORE = (float*)(ws + ((size_t)32 << 20));                  // 2 MB
    unsigned char* LABMAX = (unsigned char*)(ws + ((size_t)34 << 20)); // 512 KB

    float* E     = (float*)d_out;
    float* heads = E + (size_t)B_ * L_ * T_ * T_;
    float* tags  = heads + (size_t)B_ * T_;

    dim3 thr(256);
    // fused projections + bias + ELU (one launch, 640 blocks)
    proj_gemm_k<<<dim3(10, 64), thr, 0, stream>>>(X, Wha, bha, Wda, bda, Whl, bhl, Wdl, bdl,
                                                  HA, DA, HL, DL);
    // TA = HA @ U_arc
    gemm_k<<<dim3(4, 64, 1), thr, 0, stream>>>(HA, Ua, nullptr, TA, 512, 512, 512, 512, 0, 0, 0, (long long)128 * 512, 0);
    // DLt[b][s][j]
    transpose_k<<<dim3(4, 4, 32), dim3(32, 8), 0, stream>>>(DL, DLt);
    // arc_scores[b] = TA_b @ DA_b^T
    gemm_k<<<dim3(1, 2, 32), thr, 0, stream>>>(TA, DA, nullptr, ARC, 512, 512, 512, 128, 65536, 65536, 16384, 0, 4);
    // log_softmax over i, in place
    arc_logsoftmax_k<<<32, 128, 0, stream>>>(ARC);
    // fused: E[b,l] = (HL_b @ U_lab[l]) @ DLt_b  (two gemm_k bodies per block)
    tl_lab_k<<<dim3(50, 32, 2), thr, 0, stream>>>(HL, Ul, DLt, E);
    // label log-softmax + combine with norm_arc + exp + fused score/argmax
    energy_combine_k<<<2048, 256, 0, stream>>>(E, ARC, SCORE, LABMAX);
    // MST decode (quad-unrolled phases, lane-per-rep rescans)
    mst_k<<<32, 256, 0, stream>>>(SCORE, LABMAX, heads, tags);
}

// Round 10
// 885.629 us; speedup vs baseline: 1.4029x; 1.4029x over previous
//
#include <hip/hip_runtime.h>
#include <math.h>

#define B_ 32
#define T_ 128
#define D_ 768
#define A_ 512
#define R_ 128
#define L_ 50

// ---------------------------------------------------------------------------
// Fused projection GEMM: HA/DA/HL/DL = ELU(X @ W + b) in one launch.
// ---------------------------------------------------------------------------
__global__ __launch_bounds__(256)
void proj_gemm_k(const float* __restrict__ X,
                 const float* __restrict__ Wha, const float* __restrict__ bha,
                 const float* __restrict__ Wda, const float* __restrict__ bda,
                 const float* __restrict__ Whl, const float* __restrict__ bhl,
                 const float* __restrict__ Wdl, const float* __restrict__ bdl,
                 float* __restrict__ HA, float* __restrict__ DA,
                 float* __restrict__ HL, float* __restrict__ DL)
{
    __shared__ float As[16][68];
    __shared__ float Bs[16][132];
    const int bx = blockIdx.x;
    const float *W, *bias; float* C; int ld, ncol;
    if (bx < 4)      { W = Wha; bias = bha; C = HA; ld = 512; ncol = bx * 128; }
    else if (bx < 8) { W = Wda; bias = bda; C = DA; ld = 512; ncol = (bx - 4) * 128; }
    else if (bx == 8){ W = Whl; bias = bhl; C = HL; ld = 128; ncol = 0; }
    else             { W = Wdl; bias = bdl; C = DL; ld = 128; ncol = 0; }
    const int m0 = blockIdx.y * 64;
    const int tid = threadIdx.x;
    const int tx = tid & 15, ry = tid >> 4;
    float acc[4][8] = {};
    for (int k0 = 0; k0 < 768; k0 += 16) {
        {
            int row = tid >> 2, kb = (tid & 3) * 4;
            float4 a = *(const float4*)&X[(size_t)(m0 + row) * 768 + k0 + kb];
            As[kb + 0][row] = a.x; As[kb + 1][row] = a.y;
            As[kb + 2][row] = a.z; As[kb + 3][row] = a.w;
        }
        {
            int kk = tid >> 4, c0 = (tid & 15) * 4;
            const float* Bp = &W[(size_t)(k0 + kk) * ld + ncol + c0];
            *(float4*)&Bs[kk][c0] = *(const float4*)&Bp[0];
            *(float4*)&Bs[kk][c0 + 64] = *(const float4*)&Bp[64];
        }
        __syncthreads();
#pragma unroll
        for (int kk = 0; kk < 16; ++kk) {
            float4 a4 = *(const float4*)&As[kk][ry * 4];
            float4 b0 = *(const float4*)&Bs[kk][tx * 4];
            float4 b1 = *(const float4*)&Bs[kk][tx * 4 + 64];
            float av[4] = { a4.x, a4.y, a4.z, a4.w };
            float bv[8] = { b0.x, b0.y, b0.z, b0.w, b1.x, b1.y, b1.z, b1.w };
#pragma unroll
            for (int i = 0; i < 4; ++i)
#pragma unroll
                for (int j = 0; j < 8; ++j)
                    acc[i][j] += av[i] * bv[j];
        }
        __syncthreads();
    }
    float bv0[8];
    {
        float4 q0 = *(const float4*)&bias[ncol + tx * 4];
        float4 q1 = *(const float4*)&bias[ncol + tx * 4 + 64];
        bv0[0] = q0.x; bv0[1] = q0.y; bv0[2] = q0.z; bv0[3] = q0.w;
        bv0[4] = q1.x; bv0[5] = q1.y; bv0[6] = q1.z; bv0[7] = q1.w;
    }
#pragma unroll
    for (int i = 0; i < 4; ++i) {
        int m = m0 + ry * 4 + i;
        size_t base = (size_t)m * ld + ncol;
        float o[8];
#pragma unroll
        for (int j = 0; j < 8; ++j) {
            float v = acc[i][j] + bv0[j];
            o[j] = v > 0.0f ? v : expm1f(v);
        }
        float4 s0 = { o[0], o[1], o[2], o[3] };
        float4 s1 = { o[4], o[5], o[6], o[7] };
        *(float4*)&C[base + tx * 4] = s0;
        *(float4*)&C[base + tx * 4 + 64] = s1;
    }
}

// ---------------------------------------------------------------------------
// fp32 GEMM, tile 64x128, 256 threads, 4x8 acc/thread, b128 LDS reads.
// ---------------------------------------------------------------------------
__global__ __launch_bounds__(256)
void gemm_k(const float* __restrict__ A, const float* __restrict__ B,
            const float* __restrict__ bias, float* __restrict__ C,
            int K, int lda, int ldb, int ldc,
            long long sA, long long sB, long long sC, long long c_outer, int flags)
{
    __shared__ float As[16][68];
    __shared__ float Bs[16][132];
    A += (size_t)blockIdx.z * sA;
    B += (size_t)blockIdx.z * sB;
    C += (size_t)blockIdx.z * sC;
    const int m0 = blockIdx.y * 64, n0 = blockIdx.x * 128;
    const int tid = threadIdx.x;
    const int tx = tid & 15, ry = tid >> 4;
    float acc[4][8] = {};
    for (int k0 = 0; k0 < K; k0 += 16) {
        {
            int row = tid >> 2, kb = (tid & 3) * 4;
            float4 a = *(const float4*)&A[(size_t)(m0 + row) * lda + k0 + kb];
            As[kb + 0][row] = a.x; As[kb + 1][row] = a.y;
            As[kb + 2][row] = a.z; As[kb + 3][row] = a.w;
        }
        if (!(flags & 4)) {
            int kk = tid >> 4, c0 = (tid & 15) * 4;
            const float* Bp = &B[(size_t)(k0 + kk) * ldb + n0 + c0];
            *(float4*)&Bs[kk][c0] = *(const float4*)&Bp[0];
            *(float4*)&Bs[kk][c0 + 64] = *(const float4*)&Bp[64];
        } else {
            int col = tid >> 1, kb = (tid & 1) * 8;
            const float* Bp = &B[(size_t)(n0 + col) * ldb + k0 + kb];
            float4 b0 = *(const float4*)&Bp[0];
            float4 b1 = *(const float4*)&Bp[4];
            Bs[kb + 0][col] = b0.x; Bs[kb + 1][col] = b0.y;
            Bs[kb + 2][col] = b0.z; Bs[kb + 3][col] = b0.w;
            Bs[kb + 4][col] = b1.x; Bs[kb + 5][col] = b1.y;
            Bs[kb + 6][col] = b1.z; Bs[kb + 7][col] = b1.w;
        }
        __syncthreads();
#pragma unroll
        for (int kk = 0; kk < 16; ++kk) {
            float4 a4 = *(const float4*)&As[kk][ry * 4];
            float4 b0 = *(const float4*)&Bs[kk][tx * 4];
            float4 b1 = *(const float4*)&Bs[kk][tx * 4 + 64];
            float av[4] = { a4.x, a4.y, a4.z, a4.w };
            float bv[8] = { b0.x, b0.y, b0.z, b0.w, b1.x, b1.y, b1.z, b1.w };
#pragma unroll
            for (int i = 0; i < 4; ++i)
#pragma unroll
                for (int j = 0; j < 8; ++j)
                    acc[i][j] += av[i] * bv[j];
        }
        __syncthreads();
    }
    float bv0[8] = {};
    if (flags & 1) {
        float4 q0 = *(const float4*)&bias[n0 + tx * 4];
        float4 q1 = *(const float4*)&bias[n0 + tx * 4 + 64];
        bv0[0] = q0.x; bv0[1] = q0.y; bv0[2] = q0.z; bv0[3] = q0.w;
        bv0[4] = q1.x; bv0[5] = q1.y; bv0[6] = q1.z; bv0[7] = q1.w;
    }
#pragma unroll
    for (int i = 0; i < 4; ++i) {
        int m = m0 + ry * 4 + i;
        size_t base = (size_t)(m >> 7) * c_outer + (size_t)(m & 127) * ldc + n0;
        float o[8];
#pragma unroll
        for (int j = 0; j < 8; ++j) {
            float v = acc[i][j] + bv0[j];
            if (flags & 2) v = v > 0.0f ? v : expm1f(v);
            o[j] = v;
        }
        float4 s0 = { o[0], o[1], o[2], o[3] };
        float4 s1 = { o[4], o[5], o[6], o[7] };
        *(float4*)&C[base + tx * 4] = s0;
        *(float4*)&C[base + tx * 4 + 64] = s1;
    }
}

// 128x128 per-batch transpose: DLt[b][s][j] = DL[b][j][s]
__global__ __launch_bounds__(256)
void transpose_k(const float* __restrict__ in, float* __restrict__ out)
{
    __shared__ float tile[32][33];
    int b = blockIdx.z;
    int bx = blockIdx.x, by = blockIdx.y;
    int tx = threadIdx.x, ty = threadIdx.y; // (32,8)
    const float* src = in + (size_t)b * T_ * R_;
    float* dst = out + (size_t)b * T_ * R_;
#pragma unroll
    for (int r = 0; r < 4; ++r)
        tile[ty + 8 * r][tx] = src[(size_t)(by * 32 + ty + 8 * r) * 128 + bx * 32 + tx];
    __syncthreads();
#pragma unroll
    for (int r = 0; r < 4; ++r)
        dst[(size_t)(bx * 32 + ty + 8 * r) * 128 + by * 32 + tx] = tile[tx][ty + 8 * r];
}

// log_softmax over dim 1 (i) of (32,128,128), in place. thread = column j.
__global__ __launch_bounds__(128)
void arc_logsoftmax_k(float* __restrict__ arc)
{
    int b = blockIdx.x, j = threadIdx.x;
    float* base = arc + (size_t)b * T_ * T_ + j;
    float m = -INFINITY;
    for (int i = 0; i < T_; ++i) m = fmaxf(m, base[(size_t)i * T_]);
    float s = 0.0f;
    for (int i = 0; i < T_; ++i) s += expf(base[(size_t)i * T_] - m);
    float ls = m + logf(s);
    for (int i = 0; i < T_; ++i) base[(size_t)i * T_] -= ls;
}

// ---------------------------------------------------------------------------
// Fused TL + lab kernel v2: two chained gemm_k bodies (validated r8).
// ---------------------------------------------------------------------------
__global__ __launch_bounds__(256)
void tl_lab_k(const float* __restrict__ HL, const float* __restrict__ Ul,
              const float* __restrict__ dlt, float* __restrict__ E)
{
    __shared__ float Ts[128 * 68];  // 34816 B: [s][row], k-major for Phase B
    __shared__ float As[16][68];
    __shared__ float Bs[16][132];
    const int l = blockIdx.x, b = blockIdx.y;
    const int m0 = blockIdx.z * 64;
    const int tid = threadIdx.x;
    const int tx = tid & 15, ry = tid >> 4;
    const float* Apan = HL + (size_t)b * 16384 + (size_t)m0 * 128;
    const float* Bpan = Ul + (size_t)l * 16384;
    const float* Dpan = dlt + (size_t)b * 16384;
    float acc[4][8] = {};
    // ---- Phase A: T64 = HL_b[m0:m0+64] @ Ul_l (gemm_k body, K=128) ----
    for (int k0 = 0; k0 < 128; k0 += 16) {
        {
            int row = tid >> 2, kb = (tid & 3) * 4;
            float4 a = *(const float4*)&Apan[(size_t)row * 128 + k0 + kb];
            As[kb + 0][row] = a.x; As[kb + 1][row] = a.y;
            As[kb + 2][row] = a.z; As[kb + 3][row] = a.w;
        }
        {
            int kk = tid >> 4, c0 = (tid & 15) * 4;
            const float* Bp = &Bpan[(size_t)(k0 + kk) * 128 + c0];
            *(float4*)&Bs[kk][c0] = *(const float4*)&Bp[0];
            *(float4*)&Bs[kk][c0 + 64] = *(const float4*)&Bp[64];
        }
        __syncthreads();
#pragma unroll
        for (int kk = 0; kk < 16; ++kk) {
            float4 a4 = *(const float4*)&As[kk][ry * 4];
            float4 b0 = *(const float4*)&Bs[kk][tx * 4];
            float4 b1 = *(const float4*)&Bs[kk][tx * 4 + 64];
            float av[4] = { a4.x, a4.y, a4.z, a4.w };
            float bv[8] = { b0.x, b0.y, b0.z, b0.w, b1.x, b1.y, b1.z, b1.w };
#pragma unroll
            for (int i = 0; i < 4; ++i)
#pragma unroll
                for (int j = 0; j < 8; ++j)
                    acc[i][j] += av[i] * bv[j];
        }
        __syncthreads();
    }
    // ---- park T64 into Ts[s][row] (k-major; one-time 8 writes/thread) ----
#pragma unroll
    for (int j = 0; j < 8; ++j) {
        int col = (j < 4) ? (tx * 4 + j) : (64 + tx * 4 + j - 4);
        float4 w = { acc[0][j], acc[1][j], acc[2][j], acc[3][j] };
        *(float4*)&Ts[col * 68 + ry * 4] = w;
#pragma unroll
        for (int i = 0; i < 4; ++i) acc[i][j] = 0.0f;
    }
    __syncthreads();
    // ---- Phase B: E64 = T64 @ DLt_b (gemm_k body; A from Ts, no restage) ----
    for (int k0 = 0; k0 < 128; k0 += 16) {
        {
            int kk = tid >> 4, c0 = (tid & 15) * 4;
            const float* Bp = &Dpan[(size_t)(k0 + kk) * 128 + c0];
            *(float4*)&Bs[kk][c0] = *(const float4*)&Bp[0];
            *(float4*)&Bs[kk][c0 + 64] = *(const float4*)&Bp[64];
        }
        __syncthreads();
#pragma unroll
        for (int kk = 0; kk < 16; ++kk) {
            float4 a4 = *(const float4*)&Ts[(k0 + kk) * 68 + ry * 4];
            float4 b0 = *(const float4*)&Bs[kk][tx * 4];
            float4 b1 = *(const float4*)&Bs[kk][tx * 4 + 64];
            float av[4] = { a4.x, a4.y, a4.z, a4.w };
            float bv[8] = { b0.x, b0.y, b0.z, b0.w, b1.x, b1.y, b1.z, b1.w };
#pragma unroll
            for (int i = 0; i < 4; ++i)
#pragma unroll
                for (int j = 0; j < 8; ++j)
                    acc[i][j] += av[i] * bv[j];
        }
        __syncthreads();
    }
    float* base = E + ((size_t)b * L_ + l) * 16384 + (size_t)m0 * 128;
#pragma unroll
    for (int i = 0; i < 4; ++i) {
        float4 s0 = { acc[i][0], acc[i][1], acc[i][2], acc[i][3] };
        float4 s1 = { acc[i][4], acc[i][5], acc[i][6], acc[i][7] };
        *(float4*)&base[(size_t)(ry * 4 + i) * 128 + tx * 4] = s0;
        *(float4*)&base[(size_t)(ry * 4 + i) * 128 + tx * 4 + 64] = s1;
    }
}

// energy combine + fused score/labmax for MST.
__global__ __launch_bounds__(256)
void energy_combine_k(float* __restrict__ E, const float* __restrict__ narc,
                      float* __restrict__ score_g, unsigned char* __restrict__ labmax_g)
{
    int g = blockIdx.x * 256 + threadIdx.x; // 0..524287
    int b = g >> 14;
    int ij = g & 16383;
    float* base = E + (size_t)b * L_ * T_ * T_ + ij;
    float v[L_];
    float m = -INFINITY;
    int am = 0;
#pragma unroll
    for (int l = 0; l < L_; ++l) {
        v[l] = base[(size_t)l * T_ * T_];
        if (v[l] > m) { m = v[l]; am = l; }
    }
    float s = 0.0f;
#pragma unroll
    for (int l = 0; l < L_; ++l) s += expf(v[l] - m);
    float ls = m + logf(s);
    float na = narc[(size_t)b * T_ * T_ + ij];
#pragma unroll
    for (int l = 0; l < L_; ++l) base[(size_t)l * T_ * T_] = expf(na + v[l] - ls);
    int i = ij >> 7, j = ij & 127;
    score_g[(size_t)b * 16384 + ij] = (i == j) ? 0.0f : expf(na + m - ls);
    labmax_g[(size_t)b * 16384 + ij] = (unsigned char)am;
}

// ---------------------------------------------------------------------------
// Chu-Liu-Edmonds MST decode (r7/r8 structure — validated best, ~284 us).
// ---------------------------------------------------------------------------
__global__ __launch_bounds__(256)
void mst_k(const float* __restrict__ score_g, const unsigned char* __restrict__ labmax_g,
           float* __restrict__ heads, float* __restrict__ tags)
{
    const int b = blockIdx.x, t = threadIdx.x;
    __shared__ float score[128 * 129];          // 66 KB, stride 129
    __shared__ unsigned short oio[128 * 129];   // 33 KB: oin | (oout<<8)
    __shared__ unsigned char pstL[96 * 128];    // 12 KB: parents per pass-level
    __shared__ unsigned char kynL[96 * 128];    // 12 KB: key cand per pass-level
    __shared__ int parents[128];
    __shared__ int fe[128]; // -2 = absent; -1 = root marker
    __shared__ float pmx[128];
    __shared__ int pp[128];
    __shared__ float cwacc[128];   // cycle weight by cid
    __shared__ int cnt[128];
    __shared__ int offarr[128];
    __shared__ float Lsub[128];
    __shared__ unsigned char Lnode[128], Lcid[128];
    __shared__ unsigned char cidarr[128], oncyc[128];

    // ---- phase 0: stage score (padded), init oio/fe ----
    {
        const float4* src = (const float4*)(score_g + (size_t)b * 16384);
        for (int i = t; i < 4096; i += 256) {
            float4 v = src[i];
            int r = i >> 5, c = (i & 31) * 4;
            float* d = &score[r * 129 + c];
            d[0] = v.x; d[1] = v.y; d[2] = v.z; d[3] = v.w;
        }
    }
    for (int i = t; i < 16384; i += 256) {
        int r = i >> 7, c = i & 127;
        oio[r * 129 + c] = (unsigned short)(r | (c << 8));
    }
    if (t < 128) { fe[t] = -2; oncyc[t] = 0; }
    __syncthreads();
    if (t < 128) score[t * 129 + t] = -INFINITY; // diag never read elsewhere
    __syncthreads();
    // ---- initial full parent scan (split across 256 threads) ----
    float mxl = 0.0f; int pl = 0;
    if (t >= 128) {
        int col = t - 128;
        float mx = -INFINITY; int pu = 64;
        if (col != 0) {
            mx = score[64 * 129 + col];
#pragma unroll 16
            for (int n2 = 65; n2 < 128; ++n2) {
                float sc = score[n2 * 129 + col];
                if (sc > mx) { mx = sc; pu = n2; }
            }
        }
        pmx[col] = mx; pp[col] = pu;
    } else if (t != 0) {
        mxl = score[t]; pl = 0; // row 0 initial (root candidate)
#pragma unroll 16
        for (int n2 = 1; n2 < 64; ++n2) {
            float sc = score[n2 * 129 + t];
            if (sc > mxl) { mxl = sc; pl = n2; }
        }
    }
    __syncthreads();
    if (t == 0) parents[0] = -1;
    else if (t < 128) parents[t] = (pmx[t] > mxl) ? pp[t] : pl;
    __syncthreads(); // ---- barrier A: wave 0 takes over ----

    if (t < 64) {
        const int n0 = t, n1 = t + 64;
        int p0 = parents[n0], p1 = parents[n1];
        int c0 = 1, c1 = 1;       // active flags
        int r0 = n0, r1 = n1;     // rep_of mirrors
        int lev = 0, nact = 128, pass = 0;
        for (;;) {
            // --- doubling: a = 2^rounds-step ancestor, m = path-min ---
            int rounds = 32 - __clz(nact - 1);
            int a0 = (n0 == 0 || !c0) ? 0 : p0;
            int a1 = (!c1) ? 0 : p1;
            int m0 = n0, m1 = n1;
            for (int s = 0; s < rounds; ++s) {
                int pk0 = (a0 << 7) | m0;
                int pk1 = (a1 << 7) | m1;
                int q00 = __shfl(pk0, a0 & 63, 64);
                int q01 = __shfl(pk1, a0 & 63, 64);
                int q10 = __shfl(pk0, a1 & 63, 64);
                int q11 = __shfl(pk1, a1 & 63, 64);
                int g0 = (a0 & 64) ? q01 : q00;
                int g1 = (a1 & 64) ? q11 : q10;
                a0 = g0 >> 7; int gm0 = g0 & 127; m0 = gm0 < m0 ? gm0 : m0;
                a1 = g1 >> 7; int gm1 = g1 & 127; m1 = gm1 < m1 ? gm1 : m1;
            }
            int pred0 = (n0 >= 1) && c0 && (a0 != 0);
            int pred1 = c1 && (a1 != 0);
            unsigned long long bal0 = __ballot(pred0);
            unsigned long long bal1 = __ballot(pred1);
            if (bal0 == 0ull && bal1 == 0ull) {
                // base case: no cycles — emit final edges for active nodes
                if (n0 == 0) fe[0] = -1;
                else if (c0) { int w = oio[p0 * 129 + n0]; fe[w >> 8] = w & 255; }
                if (c1) { int w = oio[p1 * 129 + n1]; fe[w >> 8] = w & 255; }
                __threadfence_block();
                break;
            }
            // --- mark all cycle nodes; zero per-pass accumulators ---
            unsigned char ep = (unsigned char)(++pass);
            if (pred0) oncyc[a0] = ep;
            if (pred1) oncyc[a1] = ep;
            cnt[n0] = 0; cnt[n1] = 0;
            cwacc[n0] = 0.0f; cwacc[n1] = 0.0f;
            __threadfence_block(); // fence A
            int onc0 = c0 && (oncyc[n0] == ep);
            int onc1 = c1 && (oncyc[n1] == ep);
            const int cid0 = m0, cid1 = m1; // valid when onc
            cidarr[n0] = onc0 ? (unsigned char)cid0 : 0xFF;
            cidarr[n1] = onc1 ? (unsigned char)cid1 : 0xFF;
            float sub0 = 0.0f, sub1 = 0.0f;
            int rk0 = 0, rk1 = 0;
            if (onc0) { sub0 = score[p0 * 129 + n0]; rk0 = atomicAdd(&cnt[cid0], 1); atomicAdd(&cwacc[cid0], sub0); }
            if (onc1) { sub1 = score[p1 * 129 + n1]; rk1 = atomicAdd(&cnt[cid1], 1); atomicAdd(&cwacc[cid1], sub1); }
            __threadfence_block(); // fence B: cnt/cidarr/cwacc final
            // --- packed wave scan of cnt -> segment offsets (cid order) ---
            int x0 = cnt[n0], x1 = cnt[n1];
            int v = (x0 & 0xFFFF) | (x1 << 16);
            for (int off = 1; off < 64; off <<= 1) {
                int u = __shfl(v, t >= off ? t - off : 0, 64);
                v += (t >= off) ? u : 0;
            }
            int tot = __shfl(v, 63, 64);
            int Mtot = (tot & 0xFFFF) + (tot >> 16);
            offarr[n0] = (v & 0xFFFF) - x0;
            offarr[n1] = (tot & 0xFFFF) + ((v >> 16) & 0xFFFF) - x1;
            __threadfence_block(); // fence C: offsets visible
            if (onc0) { int sl = offarr[cid0] + rk0; Lnode[sl] = (unsigned char)n0; Lcid[sl] = (unsigned char)cid0; Lsub[sl] = sub0; }
            if (onc1) { int sl = offarr[cid1] + rk1; Lnode[sl] = (unsigned char)n1; Lcid[sl] = (unsigned char)cid1; Lsub[sl] = sub1; }
            // --- save pass-level state ---
            int rc0 = cidarr[r0], rc1 = cidarr[r1];
            if (lev < 96) {
                pstL[lev * 128 + n0] = (unsigned char)p0;
                pstL[lev * 128 + n1] = (unsigned char)p1;
                kynL[lev * 128 + n0] = (rc0 != 0xFF) ? (unsigned char)r0 : 0xFF;
                kynL[lev * 128 + n1] = (rc1 != 0xFF) ? (unsigned char)r1 : 0xFF;
            }
            if (rc0 != 0xFF) r0 = rc0;
            if (rc1 != 0xFF) r1 = rc1;
            __threadfence_block(); // fence D: list + saved state visible
            // --- Phase 1: all (node, cycle) pairs with rep(c) < cid(node) ---
            {
                int lim0 = c0 ? (onc0 ? cid0 : 256) : -1;
                int lim1 = c1 ? (onc1 ? cid1 : 256) : -1;
                float inw0 = -INFINITY, outw0 = -INFINITY;
                float inw1 = -INFINITY, outw1 = -INFINITY;
                int qi0 = 0, qo0 = 0, qi1 = 0, qo1 = 0;
                int cidC = Lcid[0], mC = Lnode[0];
                float sbC = Lsub[0];
                for (int i = 0; i < Mtot; ++i) {
                    int cidN = 0, mN = 0; float sbN = 0.0f;
                    if (i + 1 < Mtot) { cidN = Lcid[i + 1]; mN = Lnode[i + 1]; sbN = Lsub[i + 1]; }
                    if (cidC < lim0) {
                        float si = score[mC * 129 + n0];
                        float so = score[n0 * 129 + mC] - sbC;
                        int wi = oio[mC * 129 + n0];
                        int wo = oio[n0 * 129 + mC];
                        if (si > inw0) { inw0 = si; qi0 = wi; }
                        if (so > outw0) { outw0 = so; qo0 = wo; }
                    }
                    if (cidC < lim1) {
                        float si = score[mC * 129 + n1];
                        float so = score[n1 * 129 + mC] - sbC;
                        int wi = oio[mC * 129 + n1];
                        int wo = oio[n1 * 129 + mC];
                        if (si > inw1) { inw1 = si; qi1 = wi; }
                        if (so > outw1) { outw1 = so; qo1 = wo; }
                    }
                    int segend = (i + 1 == Mtot) || (cidN != cidC);
                    if (segend) {
                        if (cidC < lim0) {
                            float cwc = cwacc[cidC];
                            score[cidC * 129 + n0] = inw0; oio[cidC * 129 + n0] = (unsigned short)qi0;
                            score[n0 * 129 + cidC] = cwc + outw0; oio[n0 * 129 + cidC] = (unsigned short)qo0;
                        }
                        if (cidC < lim1) {
                            float cwc = cwacc[cidC];
                            score[cidC * 129 + n1] = inw1; oio[cidC * 129 + n1] = (unsigned short)qi1;
                            score[n1 * 129 + cidC] = cwc + outw1; oio[n1 * 129 + cidC] = (unsigned short)qo1;
                        }
                        inw0 = -INFINITY; outw0 = -INFINITY;
                        inw1 = -INFINITY; outw1 = -INFINITY;
                    }
                    cidC = cidN; mC = mN; sbC = sbN;
                }
            }
            __threadfence_block(); // fence E: Phase 1 visible
            // --- Phase 2: rep lanes vs strictly-later cycles ---
            int rp0 = onc0 && (n0 == cid0);
            int rp1 = onc1 && (n1 == cid1);
            unsigned long long q0 = __ballot(rp0);
            unsigned long long q1 = __ballot(rp1);
            int ncyc = (int)__popcll(q0) + (int)__popcll(q1);
            if (ncyc >= 2) {
                float inw0 = -INFINITY, outw0 = -INFINITY;
                float inw1 = -INFINITY, outw1 = -INFINITY;
                int qi0 = 0, qo0 = 0, qi1 = 0, qo1 = 0;
                int cidC = Lcid[0], mC = Lnode[0];
                float sbC = Lsub[0];
                for (int i = 0; i < Mtot; ++i) {
                    int cidN = 0, mN = 0; float sbN = 0.0f;
                    if (i + 1 < Mtot) { cidN = Lcid[i + 1]; mN = Lnode[i + 1]; sbN = Lsub[i + 1]; }
                    int e0 = rp0 && (cidC > cid0);
                    int e1 = rp1 && (cidC > cid1);
                    if (e0) {
                        float si = score[mC * 129 + n0];
                        float so = score[n0 * 129 + mC] - sbC;
                        int wi = oio[mC * 129 + n0];
                        int wo = oio[n0 * 129 + mC];
                        if (si > inw0) { inw0 = si; qi0 = wi; }
                        if (so > outw0) { outw0 = so; qo0 = wo; }
                    }
                    if (e1) {
                        float si = score[mC * 129 + n1];
                        float so = score[n1 * 129 + mC] - sbC;
                        int wi = oio[mC * 129 + n1];
                        int wo = oio[n1 * 129 + mC];
                        if (si > inw1) { inw1 = si; qi1 = wi; }
                        if (so > outw1) { outw1 = so; qo1 = wo; }
                    }
                    int segend = (i + 1 == Mtot) || (cidN != cidC);
                    if (segend) {
                        if (e0) {
                            float cwc = cwacc[cidC];
                            score[cidC * 129 + n0] = inw0; oio[cidC * 129 + n0] = (unsigned short)qi0;
                            score[n0 * 129 + cidC] = cwc + outw0; oio[n0 * 129 + cidC] = (unsigned short)qo0;
                        }
                        if (e1) {
                            float cwc = cwacc[cidC];
                            score[cidC * 129 + n1] = inw1; oio[cidC * 129 + n1] = (unsigned short)qi1;
                            score[n1 * 129 + cidC] = cwc + outw1; oio[n1 * 129 + cidC] = (unsigned short)qo1;
                        }
                        inw0 = -INFINITY; outw0 = -INFINITY;
                        inw1 = -INFINITY; outw1 = -INFINITY;
                    }
                    cidC = cidN; mC = mN; sbC = sbN;
                }
                __threadfence_block(); // fence F: Phase 2 visible
            }
            // --- deactivate dying members; remap parents into reps ---
            if (onc0 && n0 != cid0) c0 = 0;
            if (onc1 && n1 != cid1) c1 = 0;
            if (c0 && n0 != 0) { int cp = cidarr[p0]; if (cp != 0xFF) p0 = cp; }
            if (c1)            { int cp = cidarr[p1]; if (cp != 0xFF) p1 = cp; }
            // --- surviving reps: column rescans, 2 butterflies interleaved ---
            {
                unsigned long long w0 = q0, w1 = q1;
                while (w0 | w1) {
                    int repA, repB = -1;
                    if (w0) { repA = (int)__ffsll((long long)w0) - 1; w0 &= w0 - 1; }
                    else    { repA = 64 + (int)__ffsll((long long)w1) - 1; w1 &= w1 - 1; }
                    if (w0) { repB = (int)__ffsll((long long)w0) - 1; w0 &= w0 - 1; }
                    else if (w1) { repB = 64 + (int)__ffsll((long long)w1) - 1; w1 &= w1 - 1; }
                    float aA = c0 ? score[n0 * 129 + repA] : -INFINITY;
                    float bA = c1 ? score[n1 * 129 + repA] : -INFINITY;
                    float aB = -INFINITY, bB = -INFINITY;
                    if (repB >= 0) {
                        aB = c0 ? score[n0 * 129 + repB] : -INFINITY;
                        bB = c1 ? score[n1 * 129 + repB] : -INFINITY;
                    }
                    float vA; int iA;
                    if (bA > aA) { vA = bA; iA = n1; } else { vA = aA; iA = n0; }
                    float vB; int iB;
                    if (bB > aB) { vB = bB; iB = n1; } else { vB = aB; iB = n0; }
#pragma unroll
                    for (int off = 32; off >= 1; off >>= 1) {
                        float oA = __shfl_xor(vA, off, 64);
                        int jA = __shfl_xor(iA, off, 64);
                        float oB = __shfl_xor(vB, off, 64);
                        int jB = __shfl_xor(iB, off, 64);
                        if (oA > vA || (oA == vA && jA < iA)) { vA = oA; iA = jA; }
                        if (oB > vB || (oB == vB && jB < iB)) { vB = oB; iB = jB; }
                    }
                    if (n0 == repA) p0 = iA;
                    if (n1 == repA) p1 = iA;
                    if (repB >= 0) {
                        if (n0 == repB) p0 = iB;
                        if (n1 == repB) p1 = iB;
                    }
                }
            }
            nact -= (Mtot - ncyc);
            ++lev;
        }
        // --- unwind: per-pass levels, disjoint parallel walks ---
        int ltop = lev < 96 ? lev : 96;
        for (int l2 = ltop - 1; l2 >= 0; --l2) {
            int ky0 = kynL[l2 * 128 + n0], ky1 = kynL[l2 * 128 + n1];
            int cand0 = (ky0 != 0xFF) && (fe[n0] != -2);
            int cand1 = (ky1 != 0xFF) && (fe[n1] != -2);
            if (cand0) {
                int key = ky0;
                int prev = pstL[l2 * 128 + key];
                int guard = 0;
                while (prev != key && guard++ < 130) {
                    int pp2 = pstL[l2 * 128 + prev];
                    int w = oio[pp2 * 129 + prev];
                    fe[w >> 8] = w & 255;
                    prev = pp2;
                }
            }
            if (cand1) {
                int key = ky1;
                int prev = pstL[l2 * 128 + key];
                int guard = 0;
                while (prev != key && guard++ < 130) {
                    int pp2 = pstL[l2 * 128 + prev];
                    int w = oio[pp2 * 129 + prev];
                    fe[w >> 8] = w & 255;
                    prev = pp2;
                }
            }
            __threadfence_block();
        }
    }
    __syncthreads(); // ---- barrier B: waves 1-3 rejoin ----

    // --- emit heads / head_type ---
    if (t < 128) {
        int f = fe[t];
        float h, ht;
        if (f != -2) {
            h = (float)f;
            int prow = (f < 0) ? 127 : f; // numpy negative-index semantics for root
            ht = (float)(int)labmax_g[(size_t)b * 16384 + prow * 128 + t];
        } else { h = 0.0f; ht = 1.0f; }
        heads[b * 128 + t] = h;
        tags[b * 128 + t] = ht;
    }
}

extern "C" void kernel_launch(void* const* d_in, const int* in_sizes, int n_in,
                              void* d_out, int out_size, void* d_ws, size_t ws_size,
                              hipStream_t stream)
{
    const float* X   = (const float*)d_in[0];
    const float* Wha = (const float*)d_in[1];
    const float* bha = (const float*)d_in[2];
    const float* Wda = (const float*)d_in[3];
    const float* bda = (const float*)d_in[4];
    const float* Ua  = (const float*)d_in[5];
    const float* Whl = (const float*)d_in[6];
    const float* bhl = (const float*)d_in[7];
    const float* Wdl = (const float*)d_in[8];
    const float* bdl = (const float*)d_in[9];
    const float* Ul  = (const float*)d_in[10];
    // d_in[11] = mask: all-ones in this problem; length = 128 per batch.

    char* ws = (char*)d_ws;
    float* HA    = (float*)(ws + (size_t)0);
    float* DA    = (float*)(ws + ((size_t)8 << 20));
    float* TA    = (float*)(ws + ((size_t)16 << 20));
    float* HL    = (float*)(ws + ((size_t)24 << 20));
    float* DL    = (float*)(ws + ((size_t)26 << 20));
    float* DLt   = (float*)(ws + ((size_t)28 << 20));
    float* ARC   = (float*)(ws + ((size_t)30 << 20));
    float* SCORE = (float*)(ws + ((size_t)32 << 20));                  // 2 MB
    unsigned char* LABMAX = (unsigned char*)(ws + ((size_t)34 << 20)); // 512 KB

    float* E     = (float*)d_out;
    float* heads = E + (size_t)B_ * L_ * T_ * T_;
    float* tags  = heads + (size_t)B_ * T_;

    dim3 thr(256);
    // fused projections + bias + ELU (one launch, 640 blocks)
    proj_gemm_k<<<dim3(10, 64), thr, 0, stream>>>(X, Wha, bha, Wda, bda, Whl, bhl, Wdl, bdl,
                                                  HA, DA, HL, DL);
    // TA = HA @ U_arc
    gemm_k<<<dim3(4, 64, 1), thr, 0, stream>>>(HA, Ua, nullptr, TA, 512, 512, 512, 512, 0, 0, 0, (long long)128 * 512, 0);
    // DLt[b][s][j]
    transpose_k<<<dim3(4, 4, 32), dim3(32, 8), 0, stream>>>(DL, DLt);
    // arc_scores[b] = TA_b @ DA_b^T
    gemm_k<<<dim3(1, 2, 32), thr, 0, stream>>>(TA, DA, nullptr, ARC, 512, 512, 512, 128, 65536, 65536, 16384, 0, 4);
    // log_softmax over i, in place
    arc_logsoftmax_k<<<32, 128, 0, stream>>>(ARC);
    // fused: E[b,l] = (HL_b @ U_lab[l]) @ DLt_b  (two gemm_k bodies per block)
    tl_lab_k<<<dim3(50, 32, 2), thr, 0, stream>>>(HL, Ul, DLt, E);
    // label log-softmax + combine with norm_arc + exp + fused score/argmax
    energy_combine_k<<<2048, 256, 0, stream>>>(E, ARC, SCORE, LABMAX);
    // MST decode (all cycles per pass, two-sweep sequential-equivalent)
    mst_k<<<32, 256, 0, stream>>>(SCORE, LABMAX, heads, tags);
}